// Round 10
// baseline (133.085 us; speedup 1.0000x reference)
//
#include <hip/hip_runtime.h>
#include <hip/hip_bf16.h>
#include <stdint.h>

#define N_ROWS 8192
#define DIM    768          // elements per row; == BYTES per row in int8
#define BM     256
#define BN     256
#define BKB    128          // K-tile bytes (= i8 elements)
#define KTILES (DIM / BKB)  // 6
#define NT2    (N_ROWS / BN)
#define LDS_BYTES 131072

typedef __attribute__((ext_vector_type(4)))  int   i32x4;
typedef __attribute__((ext_vector_type(16))) int   i32x16;
typedef __attribute__((ext_vector_type(4)))  float f32x4;

__device__ __forceinline__ float tstudent(float c) {
    // (1 + 0.5*(1-c))^{-1.5} = t^{-1.5}, t = 1.5 - 0.5c
    float t = 1.5f - 0.5f * c;
    float r = rsqrtf(t);
    return r * r * r;
}

// ---------------- kernel 1: row L2-normalize fp32 -> int8, fp32 diag numerator, post-quant inv-norms ----------------
__global__ __launch_bounds__(256) void norm_kernel(const float* __restrict__ z1,
                                                   const float* __restrict__ z2,
                                                   signed char* __restrict__ n1,
                                                   signed char* __restrict__ n2,
                                                   float* __restrict__ num,
                                                   float* __restrict__ inva,
                                                   float* __restrict__ invb) {
    int row = blockIdx.x;
    int t = threadIdx.x;
    const float* s1 = z1 + (size_t)row * DIM;
    const float* s2 = z2 + (size_t)row * DIM;
    float a0 = s1[t], a1 = s1[t + 256], a2 = s1[t + 512];
    float b0 = s2[t], b1 = s2[t + 256], b2 = s2[t + 512];
    float ss1 = a0 * a0 + a1 * a1 + a2 * a2;
    float ss2 = b0 * b0 + b1 * b1 + b2 * b2;
    float sd  = a0 * b0 + a1 * b1 + a2 * b2;
    for (int off = 32; off; off >>= 1) {
        ss1 += __shfl_down(ss1, off);
        ss2 += __shfl_down(ss2, off);
        sd  += __shfl_down(sd, off);
    }
    __shared__ float w1[4], w2[4], wd[4];
    __shared__ float sc1_s, sc2_s;
    if ((t & 63) == 0) { int wi = t >> 6; w1[wi] = ss1; w2[wi] = ss2; wd[wi] = sd; }
    __syncthreads();
    if (t == 0) {
        float nrm1 = fmaxf(sqrtf(w1[0] + w1[1] + w1[2] + w1[3]), 1e-8f);
        float nrm2 = fmaxf(sqrtf(w2[0] + w2[1] + w2[2] + w2[3]), 1e-8f);
        float dot  = wd[0] + wd[1] + wd[2] + wd[3];
        sc1_s = 127.0f / nrm1;
        sc2_s = 127.0f / nrm2;
        num[row] = tstudent(dot / (nrm1 * nrm2));   // numerator exact in fp32
    }
    __syncthreads();
    float sc1 = sc1_s, sc2 = sc2_s;
    // quantize: q = clamp(round(127 * x_hat))
    float qa0 = fminf(fmaxf(rintf(a0 * sc1), -127.f), 127.f);
    float qa1 = fminf(fmaxf(rintf(a1 * sc1), -127.f), 127.f);
    float qa2 = fminf(fmaxf(rintf(a2 * sc1), -127.f), 127.f);
    float qb0 = fminf(fmaxf(rintf(b0 * sc2), -127.f), 127.f);
    float qb1 = fminf(fmaxf(rintf(b1 * sc2), -127.f), 127.f);
    float qb2 = fminf(fmaxf(rintf(b2 * sc2), -127.f), 127.f);
    signed char* d1 = n1 + (size_t)row * DIM;
    signed char* d2 = n2 + (size_t)row * DIM;
    d1[t]       = (signed char)(int)qa0;
    d1[t + 256] = (signed char)(int)qa1;
    d1[t + 512] = (signed char)(int)qa2;
    d2[t]       = (signed char)(int)qb0;
    d2[t + 256] = (signed char)(int)qb1;
    d2[t + 512] = (signed char)(int)qb2;
    // post-quantization inverse norms (exact correction factors for cos)
    float sq1 = qa0 * qa0 + qa1 * qa1 + qa2 * qa2;   // integer-valued, exact in fp32
    float sq2 = qb0 * qb0 + qb1 * qb1 + qb2 * qb2;
    for (int off = 32; off; off >>= 1) {
        sq1 += __shfl_down(sq1, off);
        sq2 += __shfl_down(sq2, off);
    }
    __shared__ float wq1[4], wq2[4];
    if ((t & 63) == 0) { int wi = t >> 6; wq1[wi] = sq1; wq2[wi] = sq2; }
    __syncthreads();
    if (t == 0) {
        inva[row] = rsqrtf(wq1[0] + wq1[1] + wq1[2] + wq1[3]);
        invb[row] = rsqrtf(wq2[0] + wq2[1] + wq2[2] + wq2[3]);
    }
}

// ---------------- kernel 2: 256x256 8-wave int8 MFMA GEMM, 32x32x32 shape, R9 schedule ----------------
// LDS / staging / swizzle / vmcnt ledger IDENTICAL to R9 (row = 128 B, slot = granule ^ (row&7),
// linear LDS dest + inverse-swizzled global source; stage B0,B1|B2,B3|A0,A2|A1,A3 @ 2/phase;
// VMW(4)@ph1 drains late-A(kt); VMW(2)@ph3 drains B+early-A(kt+1); invariant [A1,A3] in flight).
// MFMA: mfma_i32_32x32x32_i8 — per wave: 4 m-tiles (q = rows q*32..q*32+31, same row span as
// R9's quads -> same stage-j dependencies) x 2 n-tiles x 4 k-instr = 32 instr/tile (was 64),
// +12% pipe rate (4404 vs 3944 TOPS). Fragment: lane row/col = l&31, 16 k-bytes at true
// granule 2*ki + (l>>5); slot = granule ^ (l&7) -> one b128 per instr, conflict-free
// (each 16B granule-position served by exactly 8 lanes). A and B use the same lane->k map,
// so any internal k-permutation cancels (same symmetry validated by R1-R9 passing).
// C/D map (verified m74/m101): col = l&31, row = (reg&3) + 8*(reg>>2) + 4*(l>>5).

__device__ __forceinline__ void stG(const signed char* g, char* lds, int t, int j) {
    __builtin_amdgcn_global_load_lds(
        (const __attribute__((address_space(1))) void*)(g + (size_t)j * 64 * DIM),
        (__attribute__((address_space(3))) void*)(lds + t * 16 + j * 8192), 16, 0, 0);
}

#define BAR()  asm volatile("s_barrier" ::: "memory")
#define VMW(n) asm volatile("s_waitcnt vmcnt(" #n ")" ::: "memory")

#define READ_AQ(set, Abase, q)                                                  \
    set[0] = *(const i32x4*)((Abase) + rbA + (q) * 4096 + sg0);                 \
    set[1] = *(const i32x4*)((Abase) + rbA + (q) * 4096 + sg1);                 \
    set[2] = *(const i32x4*)((Abase) + rbA + (q) * 4096 + sg2);                 \
    set[3] = *(const i32x4*)((Abase) + rbA + (q) * 4096 + sg3);

#define READ_BN0(dst, Bbase)                                                    \
    dst[0] = *(const i32x4*)((Bbase) + rbB + sg0);                              \
    dst[1] = *(const i32x4*)((Bbase) + rbB + sg1);                              \
    dst[2] = *(const i32x4*)((Bbase) + rbB + sg2);                              \
    dst[3] = *(const i32x4*)((Bbase) + rbB + sg3);

#define READ_BN1(Bbase)                                                         \
    bN1[0] = *(const i32x4*)((Bbase) + rbB + 4096 + sg0);                       \
    bN1[1] = *(const i32x4*)((Bbase) + rbB + 4096 + sg1);                       \
    bN1[2] = *(const i32x4*)((Bbase) + rbB + 4096 + sg2);                       \
    bN1[3] = *(const i32x4*)((Bbase) + rbB + 4096 + sg3);

#define MFMA_Q(q, AS, BN0)                                                                                   \
    __builtin_amdgcn_s_setprio(1);                                                                           \
    _Pragma("unroll")                                                                                        \
    for (int ki = 0; ki < 4; ++ki) {                                                                         \
        acc[(q)][0] = __builtin_amdgcn_mfma_i32_32x32x32_i8(AS[ki], BN0[ki], acc[(q)][0], 0, 0, 0);          \
        acc[(q)][1] = __builtin_amdgcn_mfma_i32_32x32x32_i8(AS[ki], bN1[ki], acc[(q)][1], 0, 0, 0);          \
    }                                                                                                        \
    __builtin_amdgcn_s_setprio(0);

#define TILE(kt, B0c, B0n, PAR)                                                 \
    {                                                                           \
        const char* Ab  = smem + (PAR) * 32768;                                 \
        const char* Bb  = smem + 65536 + (PAR) * 32768;                         \
        const char* AbN = smem + ((PAR) ^ 1) * 32768;                           \
        const char* BbN = smem + 65536 + ((PAR) ^ 1) * 32768;                   \
        char* AnW = smem + ((PAR) ^ 1) * 32768;                                 \
        char* BnW = smem + 65536 + ((PAR) ^ 1) * 32768;                         \
        const signed char* Agn = Ag + ((kt) + 1) * BKB;                         \
        const signed char* Bgn = Bg + ((kt) + 1) * BKB;                         \
        /* ph0 */                                                               \
        stG(Bgn, BnW, t, 0); stG(Bgn, BnW, t, 1);                               \
        READ_BN1(Bb);                                                           \
        READ_AQ(aS1, Ab, 1);                                                    \
        MFMA_Q(0, aS0, B0c);                                                    \
        /* ph1 */                                                               \
        stG(Bgn, BnW, t, 2); stG(Bgn, BnW, t, 3);                               \
        VMW(4); BAR();                                                          \
        READ_AQ(aS0, Ab, 2);                                                    \
        MFMA_Q(1, aS1, B0c);                                                    \
        /* ph2 */                                                               \
        stG(Agn, AnW, t, 0); stG(Agn, AnW, t, 2);                               \
        READ_AQ(aS1, Ab, 3);                                                    \
        MFMA_Q(2, aS0, B0c);                                                    \
        /* ph3 */                                                               \
        stG(Agn, AnW, t, 1); stG(Agn, AnW, t, 3);                               \
        VMW(2); BAR();                                                          \
        READ_BN0(B0n, BbN);                                                     \
        READ_AQ(aS0, AbN, 0);                                                   \
        MFMA_Q(3, aS1, B0c);                                                    \
    }

__global__ __launch_bounds__(512, 2) void gemm_kernel(const signed char* __restrict__ n1,
                                                      const signed char* __restrict__ n2,
                                                      const float* __restrict__ inva,
                                                      const float* __restrict__ invb,
                                                      float* __restrict__ partial) {
    extern __shared__ char smem[];
    int t = threadIdx.x;
    int l = t & 63;
    int w = t >> 6;
    int wr = w >> 2;   // 0..1 -> A half (128 rows)
    int wc = w & 3;    // 0..3 -> B quarter (64 cols)

    // XCD-aware + L2 supertile mapping (1024 blocks, bijective)
    int bid = blockIdx.x;
    int xcd = bid & 7, idx = bid >> 3;
    int br = xcd * 4 + (idx & 3);
    int bc = (idx >> 4) * 4 + ((idx >> 2) & 3);
    int rowbase = br * BM, colbase = bc * BN;

    // staging: thread t covers LDS rows (t>>3)+64j, granule t&7;
    // inverse-swizzled global 16B-granule = (t&7) ^ ((t>>3)&7)
    int sr = t >> 3;
    int gcol0 = ((t & 7) ^ (sr & 7)) * 16;
    const signed char* Ag = n1 + (size_t)(rowbase + sr) * DIM + gcol0;
    const signed char* Bg = n2 + (size_t)(colbase + sr) * DIM + gcol0;

    i32x16 acc[4][2] = {};

    // read side: frag row r = l&31 (r&7 == l&7), true granule(ki) = 2*ki + (l>>5),
    // slot = granule ^ (l&7)
    int h = l >> 5;
    int sg0 = ((2 * 0 + h) ^ (l & 7)) * 16;
    int sg1 = ((2 * 1 + h) ^ (l & 7)) * 16;
    int sg2 = ((2 * 2 + h) ^ (l & 7)) * 16;
    int sg3 = ((2 * 3 + h) ^ (l & 7)) * 16;
    int rbA = (wr * 128 + (l & 31)) * 128;
    int rbB = (wc * 64 + (l & 31)) * 128;

    i32x4 aS0[4], aS1[4];
    i32x4 bn0A[4], bn0B[4];
    i32x4 bN1[4];

    // prologue: stage K-tile 0 into buf0 (B0..B3, A0, A2, A1, A3)
    {
        char* A0b = smem;
        char* B0b = smem + 65536;
        stG(Bg, B0b, t, 0); stG(Bg, B0b, t, 1); stG(Bg, B0b, t, 2); stG(Bg, B0b, t, 3);
        stG(Ag, A0b, t, 0); stG(Ag, A0b, t, 2); stG(Ag, A0b, t, 1); stG(Ag, A0b, t, 3);
    }
    VMW(2);   // drains B0-3, A0, A2; leaves [A1,A3] in flight (pipeline invariant)
    BAR();
    READ_BN0(bn0A, smem + 65536);
    READ_AQ(aS0, smem, 0);

    TILE(0, bn0A, bn0B, 0)
    TILE(1, bn0B, bn0A, 1)
    TILE(2, bn0A, bn0B, 0)
    TILE(3, bn0B, bn0A, 1)
    TILE(4, bn0A, bn0B, 0)
    {   // peeled tile 5 (parity 1, B n0 prefetched in bn0B; no staging)
        const char* Ab = smem + 32768;
        const char* Bb = smem + 65536 + 32768;
        /* ph0 */
        READ_BN1(Bb);
        READ_AQ(aS1, Ab, 1);
        MFMA_Q(0, aS0, bn0B);
        /* ph1 — drain late-A of this tile before q2 reads */
        VMW(0); BAR();
        READ_AQ(aS0, Ab, 2);
        MFMA_Q(1, aS1, bn0B);
        /* ph2 */
        READ_AQ(aS1, Ab, 3);
        MFMA_Q(2, aS0, bn0B);
        /* ph3 */
        MFMA_Q(3, aS1, bn0B);
    }

    // ---------------- epilogue: cos = acc * inva[row] * invb[col]; t-Student + row sums ----------------
    // C/D map (32x32): col = wc*64 + n*32 + (l&31); row = wr*128 + q*32 + (reg&3) + 8*(reg>>2) + 4*(l>>5)
    float invb_n[2];
    #pragma unroll
    for (int n = 0; n < 2; ++n)
        invb_n[n] = invb[colbase + wc * 64 + n * 32 + (l & 31)];

    float* red = (float*)smem;
    __syncthreads();
    int hb = h * 4;
    #pragma unroll
    for (int mt = 0; mt < 4; ++mt) {
        #pragma unroll
        for (int rg = 0; rg < 4; ++rg) {
            f32x4 ia = *(const f32x4*)(inva + rowbase + wr * 128 + mt * 32 + rg * 8 + hb);
            #pragma unroll
            for (int j = 0; j < 4; ++j) {
                float c0 = (float)acc[mt][0][rg * 4 + j] * ia[j] * invb_n[0];
                float c1 = (float)acc[mt][1][rg * 4 + j] * ia[j] * invb_n[1];
                float s = tstudent(c0) + tstudent(c1);
                s += __shfl_xor(s, 1);
                s += __shfl_xor(s, 2);
                s += __shfl_xor(s, 4);
                s += __shfl_xor(s, 8);
                s += __shfl_xor(s, 16);
                if ((l & 31) == 0) {
                    int row = wr * 128 + mt * 32 + rg * 8 + hb + j;
                    red[row * 4 + wc] = s;
                }
            }
        }
    }
    __syncthreads();
    if (t < BM) {
        partial[(size_t)bc * N_ROWS + rowbase + t] = red[t * 4 + 0] + red[t * 4 + 1] + red[t * 4 + 2] + red[t * 4 + 3];
    }
}

// ---------------- kernel 3: per-row denom + ratio, per-block sums ----------------
__global__ __launch_bounds__(256) void reduce_kernel(const float* __restrict__ partial,
                                                     const float* __restrict__ num,
                                                     float* __restrict__ blocksum) {
    int row = blockIdx.x * 256 + threadIdx.x;
    float d = 0.f;
    #pragma unroll 8
    for (int ct = 0; ct < NT2; ++ct) d += partial[(size_t)ct * N_ROWS + row];
    float s = num[row] / d;
    for (int off = 32; off; off >>= 1) s += __shfl_down(s, off);
    __shared__ float wsum[4];
    if ((threadIdx.x & 63) == 0) wsum[threadIdx.x >> 6] = s;
    __syncthreads();
    if (threadIdx.x == 0) blocksum[blockIdx.x] = wsum[0] + wsum[1] + wsum[2] + wsum[3];
}

// ---------------- kernel 4: final scalar ----------------
__global__ __launch_bounds__(64) void final_kernel(const float* __restrict__ blocksum,
                                                   float* __restrict__ out) {
    int l = threadIdx.x;
    float s = (l < 32) ? blocksum[l] : 0.f;
    for (int off = 32; off; off >>= 1) s += __shfl_down(s, off);
    if (l == 0) out[0] = -(s / (float)N_ROWS);
}

extern "C" void kernel_launch(void* const* d_in, const int* in_sizes, int n_in,
                              void* d_out, int out_size, void* d_ws, size_t ws_size,
                              hipStream_t stream) {
    const float* z1 = (const float*)d_in[0];
    const float* z2 = (const float*)d_in[1];
    char* ws = (char*)d_ws;
    const size_t n_bytes = (size_t)N_ROWS * DIM;   // 6,291,456 (int8)
    signed char* n1 = (signed char*)ws;
    signed char* n2 = (signed char*)(ws + n_bytes);
    size_t base2 = 2 * n_bytes;
    float* num      = (float*)(ws + base2);                    // 32 KB
    float* inva     = (float*)(ws + base2 + 32768);            // 32 KB
    float* invb     = (float*)(ws + base2 + 65536);            // 32 KB
    float* partial  = (float*)(ws + base2 + 98304);            // 1 MB used
    float* blocksum = (float*)(ws + base2 + 98304 + 2097152);  // 128 B

    hipFuncSetAttribute((const void*)gemm_kernel,
                        hipFuncAttributeMaxDynamicSharedMemorySize, LDS_BYTES);

    norm_kernel<<<N_ROWS, 256, 0, stream>>>(z1, z2, n1, n2, num, inva, invb);
    gemm_kernel<<<NT2 * NT2, 512, LDS_BYTES, stream>>>(n1, n2, inva, invb, partial);
    reduce_kernel<<<N_ROWS / 256, 256, 0, stream>>>(partial, num, blocksum);
    final_kernel<<<1, 64, 0, stream>>>(blocksum, (float*)d_out);
}

// Round 11
// 90.078 us; speedup vs baseline: 1.4774x; 1.4774x over previous
//
#include <hip/hip_runtime.h>
#include <hip/hip_bf16.h>
#include <stdint.h>

#define N_ROWS 8192
#define DIM    768          // elements per row; == BYTES per row in int8
#define BM     256
#define BN     256
#define BKB    128          // K-tile bytes (= i8 elements)
#define KTILES (DIM / BKB)  // 6
#define NT2    (N_ROWS / BN)
#define LDS_BYTES 131072

typedef __attribute__((ext_vector_type(4)))  int   i32x4;
typedef __attribute__((ext_vector_type(4)))  float f32x4;

__device__ __forceinline__ float tstudent(float c) {
    // (1 + 0.5*(1-c))^{-1.5} = t^{-1.5}, t = 1.5 - 0.5c
    float t = 1.5f - 0.5f * c;
    float r = rsqrtf(t);
    return r * r * r;
}

// ---------------- kernel 1: row L2-normalize fp32 -> int8, fp32 diag numerator, post-quant inv-norms ----------------
__global__ __launch_bounds__(256) void norm_kernel(const float* __restrict__ z1,
                                                   const float* __restrict__ z2,
                                                   signed char* __restrict__ n1,
                                                   signed char* __restrict__ n2,
                                                   float* __restrict__ num,
                                                   float* __restrict__ inva,
                                                   float* __restrict__ invb) {
    int row = blockIdx.x;
    int t = threadIdx.x;
    const float* s1 = z1 + (size_t)row * DIM;
    const float* s2 = z2 + (size_t)row * DIM;
    float a0 = s1[t], a1 = s1[t + 256], a2 = s1[t + 512];
    float b0 = s2[t], b1 = s2[t + 256], b2 = s2[t + 512];
    float ss1 = a0 * a0 + a1 * a1 + a2 * a2;
    float ss2 = b0 * b0 + b1 * b1 + b2 * b2;
    float sd  = a0 * b0 + a1 * b1 + a2 * b2;
    for (int off = 32; off; off >>= 1) {
        ss1 += __shfl_down(ss1, off);
        ss2 += __shfl_down(ss2, off);
        sd  += __shfl_down(sd, off);
    }
    __shared__ float w1[4], w2[4], wd[4];
    __shared__ float sc1_s, sc2_s;
    if ((t & 63) == 0) { int wi = t >> 6; w1[wi] = ss1; w2[wi] = ss2; wd[wi] = sd; }
    __syncthreads();
    if (t == 0) {
        float nrm1 = fmaxf(sqrtf(w1[0] + w1[1] + w1[2] + w1[3]), 1e-8f);
        float nrm2 = fmaxf(sqrtf(w2[0] + w2[1] + w2[2] + w2[3]), 1e-8f);
        float dot  = wd[0] + wd[1] + wd[2] + wd[3];
        sc1_s = 127.0f / nrm1;
        sc2_s = 127.0f / nrm2;
        num[row] = tstudent(dot / (nrm1 * nrm2));   // numerator exact in fp32
    }
    __syncthreads();
    float sc1 = sc1_s, sc2 = sc2_s;
    float qa0 = fminf(fmaxf(rintf(a0 * sc1), -127.f), 127.f);
    float qa1 = fminf(fmaxf(rintf(a1 * sc1), -127.f), 127.f);
    float qa2 = fminf(fmaxf(rintf(a2 * sc1), -127.f), 127.f);
    float qb0 = fminf(fmaxf(rintf(b0 * sc2), -127.f), 127.f);
    float qb1 = fminf(fmaxf(rintf(b1 * sc2), -127.f), 127.f);
    float qb2 = fminf(fmaxf(rintf(b2 * sc2), -127.f), 127.f);
    signed char* d1 = n1 + (size_t)row * DIM;
    signed char* d2 = n2 + (size_t)row * DIM;
    d1[t]       = (signed char)(int)qa0;
    d1[t + 256] = (signed char)(int)qa1;
    d1[t + 512] = (signed char)(int)qa2;
    d2[t]       = (signed char)(int)qb0;
    d2[t + 256] = (signed char)(int)qb1;
    d2[t + 512] = (signed char)(int)qb2;
    float sq1 = qa0 * qa0 + qa1 * qa1 + qa2 * qa2;
    float sq2 = qb0 * qb0 + qb1 * qb1 + qb2 * qb2;
    for (int off = 32; off; off >>= 1) {
        sq1 += __shfl_down(sq1, off);
        sq2 += __shfl_down(sq2, off);
    }
    __shared__ float wq1[4], wq2[4];
    if ((t & 63) == 0) { int wi = t >> 6; wq1[wi] = sq1; wq2[wi] = sq2; }
    __syncthreads();
    if (t == 0) {
        inva[row] = rsqrtf(wq1[0] + wq1[1] + wq1[2] + wq1[3]);
        invb[row] = rsqrtf(wq2[0] + wq2[1] + wq2[2] + wq2[3]);
    }
}

// ---------------- kernel 2: 256x256 16-wave int8 MFMA GEMM (16x16x64), TLP schedule ----------------
// 1024 threads = 16 waves (4 wr x 4 wc), per-wave output 64x64 -> acc = 64 VGPR
// (fits 4 waves/SIMD at <=128 VGPR — the R8 spill trap avoided by halving per-wave acc).
// LDS / swizzle / staging formulas IDENTICAL to R9 (row = 128 B, slot = granule ^ (row&7),
// linear LDS dest + inverse-swizzled global source; sr = t>>3, granule = t&7 — with 1024
// threads one stage op covers 128 rows, so a full K-tile = 2 ops/operand = 4 ops total).
// Read geometry = R9's proven additive-seg form (seg0/seg1) -> ~1e5 bank conflicts,
// NOT R10's paired-granule form (4.8M).
// Schedule: 2 phases/tile, NO mid-tile barrier — waves free-run; stage all 4 ops for
// kt+1 at phase 0; single VMW(0)+BAR at tile end. Publish: each wave drains its own
// global_load_lds (vmcnt), barrier makes all waves' stages visible. WAR: parity-p
// stage writes issue a full tile after parity-p reads completed (reads complete
// before their consuming MFMAs, which precede the prior barrier).

__device__ __forceinline__ void stG(const signed char* g, char* lds, int t, int j) {
    __builtin_amdgcn_global_load_lds(
        (const __attribute__((address_space(1))) void*)(g + (size_t)j * 128 * DIM),
        (__attribute__((address_space(3))) void*)(lds + t * 16 + j * 16384), 16, 0, 0);
}

#define BAR()  asm volatile("s_barrier" ::: "memory")
#define VMW(n) asm volatile("s_waitcnt vmcnt(" #n ")" ::: "memory")

// ks=0 (k-bytes 0-63) pairs A seg0 with B seg0; ks=1 pairs seg1 with seg1.
#define HALF(mq)                                                                                      \
    {                                                                                                 \
        i32x4 a00 = *(const i32x4*)(Ab + rbA + ((mq)    ) * 2048 + seg0);                             \
        i32x4 a01 = *(const i32x4*)(Ab + rbA + ((mq)    ) * 2048 + seg1);                             \
        i32x4 a10 = *(const i32x4*)(Ab + rbA + ((mq) + 1) * 2048 + seg0);                             \
        i32x4 a11 = *(const i32x4*)(Ab + rbA + ((mq) + 1) * 2048 + seg1);                             \
        __builtin_amdgcn_s_setprio(1);                                                                \
        _Pragma("unroll")                                                                             \
        for (int n = 0; n < 4; ++n) {                                                                 \
            acc[(mq)][n]     = __builtin_amdgcn_mfma_i32_16x16x64_i8(a00, bS0[n], acc[(mq)][n], 0, 0, 0);     \
            acc[(mq)][n]     = __builtin_amdgcn_mfma_i32_16x16x64_i8(a01, bS1[n], acc[(mq)][n], 0, 0, 0);     \
            acc[(mq) + 1][n] = __builtin_amdgcn_mfma_i32_16x16x64_i8(a10, bS0[n], acc[(mq) + 1][n], 0, 0, 0); \
            acc[(mq) + 1][n] = __builtin_amdgcn_mfma_i32_16x16x64_i8(a11, bS1[n], acc[(mq) + 1][n], 0, 0, 0); \
        }                                                                                             \
        __builtin_amdgcn_s_setprio(0);                                                                \
    }

#define READ_B()                                                                \
    i32x4 bS0[4], bS1[4];                                                       \
    _Pragma("unroll")                                                           \
    for (int n = 0; n < 4; ++n) {                                               \
        bS0[n] = *(const i32x4*)(Bb + rbB + n * 2048 + seg0);                   \
        bS1[n] = *(const i32x4*)(Bb + rbB + n * 2048 + seg1);                   \
    }

__global__ __launch_bounds__(1024) void gemm_kernel(const signed char* __restrict__ n1,
                                                    const signed char* __restrict__ n2,
                                                    const float* __restrict__ inva,
                                                    const float* __restrict__ invb,
                                                    float* __restrict__ partial) {
    extern __shared__ char smem[];
    int t = threadIdx.x;
    int l = t & 63;
    int w = t >> 6;    // 0..15
    int wr = w >> 2;   // 0..3 -> A 64-row band
    int wc = w & 3;    // 0..3 -> B 64-col band

    // XCD-aware + L2 supertile mapping (1024 blocks, bijective)
    int bid = blockIdx.x;
    int xcd = bid & 7, idx = bid >> 3;
    int br = xcd * 4 + (idx & 3);
    int bc = (idx >> 4) * 4 + ((idx >> 2) & 3);
    int rowbase = br * BM, colbase = bc * BN;

    // staging: thread t covers LDS row sr = t>>3 (+128j), granule t&7;
    // inverse-swizzled global 16B-granule = (t&7) ^ (sr&7)
    int sr = t >> 3;
    int gcol0 = ((t & 7) ^ (sr & 7)) * 16;
    const signed char* Ag = n1 + (size_t)(rowbase + sr) * DIM + gcol0;
    const signed char* Bg = n2 + (size_t)(colbase + sr) * DIM + gcol0;

    i32x4 acc[4][4] = {};   // 64 VGPR

    // read side (R9 formulas): frag row r = l&15 (bands are multiples of 64 -> r&7 = l&7),
    // true granule = (l>>4) + 4*ks, slot = granule ^ (l&7)
    int seg0 = (((l >> 4) + 0) ^ (l & 7)) * 16;
    int seg1 = (((l >> 4) + 4) ^ (l & 7)) * 16;
    int rbA = (wr * 64 + (l & 15)) * 128;
    int rbB = (wc * 64 + (l & 15)) * 128;

    // prologue: stage K-tile 0 into parity 0
    stG(Ag, smem, t, 0);         stG(Ag, smem, t, 1);
    stG(Bg, smem + 65536, t, 0); stG(Bg, smem + 65536, t, 1);
    VMW(0); BAR();

    for (int kt = 0; kt < KTILES - 1; ++kt) {
        int db = kt & 1;
        const char* Ab = smem + db * 32768;
        const char* Bb = smem + 65536 + db * 32768;
        char* AnW = smem + (db ^ 1) * 32768;
        char* BnW = smem + 65536 + (db ^ 1) * 32768;
        const signed char* Agn = Ag + (kt + 1) * BKB;
        const signed char* Bgn = Bg + (kt + 1) * BKB;

        // phase 0: stage next tile + compute m0,m1
        stG(Agn, AnW, t, 0); stG(Agn, AnW, t, 1);
        stG(Bgn, BnW, t, 0); stG(Bgn, BnW, t, 1);
        READ_B();
        HALF(0);
        // phase 1: compute m2,m3; publish
        HALF(2);
        VMW(0); BAR();
    }
    {   // peeled last tile (kt = 5, parity 1): no staging
        const char* Ab = smem + 32768;
        const char* Bb = smem + 65536 + 32768;
        READ_B();
        HALF(0);
        HALF(2);
    }

    // ---------------- epilogue: cos = acc * inva[row] * invb[col]; t-Student + row sums ----------------
    // C/D map: row = wr*64 + m*16 + (l>>4)*4 + j (A-side), col = wc*64 + n*16 + (l&15)
    float invb_n[4];
    #pragma unroll
    for (int n = 0; n < 4; ++n)
        invb_n[n] = invb[colbase + wc * 64 + n * 16 + (l & 15)];

    float* red = (float*)smem;  // 256 rows x 4 wc
    __syncthreads();
    #pragma unroll
    for (int m = 0; m < 4; ++m) {
        f32x4 ia = *(const f32x4*)(inva + rowbase + wr * 64 + m * 16 + (l >> 4) * 4);
        #pragma unroll
        for (int j = 0; j < 4; ++j) {
            float s = 0.f;
            #pragma unroll
            for (int n = 0; n < 4; ++n) {
                float cos = (float)acc[m][n][j] * ia[j] * invb_n[n];
                s += tstudent(cos);
            }
            s += __shfl_xor(s, 1);
            s += __shfl_xor(s, 2);
            s += __shfl_xor(s, 4);
            s += __shfl_xor(s, 8);
            if ((l & 15) == 0) {
                int row = wr * 64 + m * 16 + (l >> 4) * 4 + j;
                red[row * 4 + wc] = s;
            }
        }
    }
    __syncthreads();
    if (t < BM) {
        partial[(size_t)bc * N_ROWS + rowbase + t] = red[t * 4 + 0] + red[t * 4 + 1] + red[t * 4 + 2] + red[t * 4 + 3];
    }
}

// ---------------- kernel 3: per-row denom + ratio, per-block sums ----------------
__global__ __launch_bounds__(256) void reduce_kernel(const float* __restrict__ partial,
                                                     const float* __restrict__ num,
                                                     float* __restrict__ blocksum) {
    int row = blockIdx.x * 256 + threadIdx.x;
    float d = 0.f;
    #pragma unroll 8
    for (int ct = 0; ct < NT2; ++ct) d += partial[(size_t)ct * N_ROWS + row];
    float s = num[row] / d;
    for (int off = 32; off; off >>= 1) s += __shfl_down(s, off);
    __shared__ float wsum[4];
    if ((threadIdx.x & 63) == 0) wsum[threadIdx.x >> 6] = s;
    __syncthreads();
    if (threadIdx.x == 0) blocksum[blockIdx.x] = wsum[0] + wsum[1] + wsum[2] + wsum[3];
}

// ---------------- kernel 4: final scalar ----------------
__global__ __launch_bounds__(64) void final_kernel(const float* __restrict__ blocksum,
                                                   float* __restrict__ out) {
    int l = threadIdx.x;
    float s = (l < 32) ? blocksum[l] : 0.f;
    for (int off = 32; off; off >>= 1) s += __shfl_down(s, off);
    if (l == 0) out[0] = -(s / (float)N_ROWS);
}

extern "C" void kernel_launch(void* const* d_in, const int* in_sizes, int n_in,
                              void* d_out, int out_size, void* d_ws, size_t ws_size,
                              hipStream_t stream) {
    const float* z1 = (const float*)d_in[0];
    const float* z2 = (const float*)d_in[1];
    char* ws = (char*)d_ws;
    const size_t n_bytes = (size_t)N_ROWS * DIM;   // 6,291,456 (int8)
    signed char* n1 = (signed char*)ws;
    signed char* n2 = (signed char*)(ws + n_bytes);
    size_t base2 = 2 * n_bytes;
    float* num      = (float*)(ws + base2);                    // 32 KB
    float* inva     = (float*)(ws + base2 + 32768);            // 32 KB
    float* invb     = (float*)(ws + base2 + 65536);            // 32 KB
    float* partial  = (float*)(ws + base2 + 98304);            // 1 MB used
    float* blocksum = (float*)(ws + base2 + 98304 + 2097152);  // 128 B

    hipFuncSetAttribute((const void*)gemm_kernel,
                        hipFuncAttributeMaxDynamicSharedMemorySize, LDS_BYTES);

    norm_kernel<<<N_ROWS, 256, 0, stream>>>(z1, z2, n1, n2, num, inva, invb);
    gemm_kernel<<<NT2 * NT2, 1024, LDS_BYTES, stream>>>(n1, n2, inva, invb, partial);
    reduce_kernel<<<N_ROWS / 256, 256, 0, stream>>>(partial, num, blocksum);
    final_kernel<<<1, 64, 0, stream>>>(blocksum, (float*)d_out);
}

// Round 12
// 88.498 us; speedup vs baseline: 1.5038x; 1.0179x over previous
//
#include <hip/hip_runtime.h>
#include <hip/hip_bf16.h>
#include <stdint.h>

#define N_ROWS 8192
#define DIM    768          // elements per row; == BYTES per row in int8
#define BM     256
#define BN     256
#define BKB    128          // K-tile bytes (= i8 elements)
#define KTILES (DIM / BKB)  // 6
#define NT2    (N_ROWS / BN)
#define LDS_BYTES 131072

typedef __attribute__((ext_vector_type(4)))  int   i32x4;
typedef __attribute__((ext_vector_type(4)))  float f32x4;

__device__ __forceinline__ float tstudent(float c) {
    // (1 + 0.5*(1-c))^{-1.5} = t^{-1.5}, t = 1.5 - 0.5c
    float t = 1.5f - 0.5f * c;
    float r = rsqrtf(t);
    return r * r * r;
}

// ---------------- kernel 1: row L2-normalize fp32 -> int8, fp32 diag numerator, post-quant inv-norms ----------------
__global__ __launch_bounds__(256) void norm_kernel(const float* __restrict__ z1,
                                                   const float* __restrict__ z2,
                                                   signed char* __restrict__ n1,
                                                   signed char* __restrict__ n2,
                                                   float* __restrict__ num,
                                                   float* __restrict__ inva,
                                                   float* __restrict__ invb) {
    int row = blockIdx.x;
    int t = threadIdx.x;
    const float* s1 = z1 + (size_t)row * DIM;
    const float* s2 = z2 + (size_t)row * DIM;
    float a0 = s1[t], a1 = s1[t + 256], a2 = s1[t + 512];
    float b0 = s2[t], b1 = s2[t + 256], b2 = s2[t + 512];
    float ss1 = a0 * a0 + a1 * a1 + a2 * a2;
    float ss2 = b0 * b0 + b1 * b1 + b2 * b2;
    float sd  = a0 * b0 + a1 * b1 + a2 * b2;
    for (int off = 32; off; off >>= 1) {
        ss1 += __shfl_down(ss1, off);
        ss2 += __shfl_down(ss2, off);
        sd  += __shfl_down(sd, off);
    }
    __shared__ float w1[4], w2[4], wd[4];
    __shared__ float sc1_s, sc2_s;
    if ((t & 63) == 0) { int wi = t >> 6; w1[wi] = ss1; w2[wi] = ss2; wd[wi] = sd; }
    __syncthreads();
    if (t == 0) {
        float nrm1 = fmaxf(sqrtf(w1[0] + w1[1] + w1[2] + w1[3]), 1e-8f);
        float nrm2 = fmaxf(sqrtf(w2[0] + w2[1] + w2[2] + w2[3]), 1e-8f);
        float dot  = wd[0] + wd[1] + wd[2] + wd[3];
        sc1_s = 127.0f / nrm1;
        sc2_s = 127.0f / nrm2;
        num[row] = tstudent(dot / (nrm1 * nrm2));   // numerator exact in fp32
    }
    __syncthreads();
    float sc1 = sc1_s, sc2 = sc2_s;
    float qa0 = fminf(fmaxf(rintf(a0 * sc1), -127.f), 127.f);
    float qa1 = fminf(fmaxf(rintf(a1 * sc1), -127.f), 127.f);
    float qa2 = fminf(fmaxf(rintf(a2 * sc1), -127.f), 127.f);
    float qb0 = fminf(fmaxf(rintf(b0 * sc2), -127.f), 127.f);
    float qb1 = fminf(fmaxf(rintf(b1 * sc2), -127.f), 127.f);
    float qb2 = fminf(fmaxf(rintf(b2 * sc2), -127.f), 127.f);
    signed char* d1 = n1 + (size_t)row * DIM;
    signed char* d2 = n2 + (size_t)row * DIM;
    d1[t]       = (signed char)(int)qa0;
    d1[t + 256] = (signed char)(int)qa1;
    d1[t + 512] = (signed char)(int)qa2;
    d2[t]       = (signed char)(int)qb0;
    d2[t + 256] = (signed char)(int)qb1;
    d2[t + 512] = (signed char)(int)qb2;
    float sq1 = qa0 * qa0 + qa1 * qa1 + qa2 * qa2;
    float sq2 = qb0 * qb0 + qb1 * qb1 + qb2 * qb2;
    for (int off = 32; off; off >>= 1) {
        sq1 += __shfl_down(sq1, off);
        sq2 += __shfl_down(sq2, off);
    }
    __shared__ float wq1[4], wq2[4];
    if ((t & 63) == 0) { int wi = t >> 6; wq1[wi] = sq1; wq2[wi] = sq2; }
    __syncthreads();
    if (t == 0) {
        inva[row] = rsqrtf(wq1[0] + wq1[1] + wq1[2] + wq1[3]);
        invb[row] = rsqrtf(wq2[0] + wq2[1] + wq2[2] + wq2[3]);
    }
}

// ---------------- kernel 2: 256x256 16-wave int8 MFMA GEMM (16x16x64), TLP + split-ks ----------------
// Structure identical to R11 (1024 threads = 16 waves 4x4, per-wave 64x64 out, acc = 64
// regs in AGPRs; LDS row = 128 B, slot = granule ^ (row&7); linear LDS dest + inverse-
// swizzled global source; 2 phases/tile; single VMW(0)+BAR per tile; free-running waves).
// ROUND-12 change: split-ks ordering — all ks=0 MFMAs (B seg0 live only), then ks=1
// (B seg1 reuses the same 16 regs); A-frags JIT-read 1 b128 per 4-MFMA group.
// Arch-VGPR live ~40 < 64 -> no spill (R11 had 21 MB scratch writes from bS0+bS1
// held across the whole tile). Integer adds are order-invariant -> bit-identical.

__device__ __forceinline__ void stG(const signed char* g, char* lds, int t, int j) {
    __builtin_amdgcn_global_load_lds(
        (const __attribute__((address_space(1))) void*)(g + (size_t)j * 128 * DIM),
        (__attribute__((address_space(3))) void*)(lds + t * 16 + j * 16384), 16, 0, 0);
}

#define BAR()  asm volatile("s_barrier" ::: "memory")
#define VMW(n) asm volatile("s_waitcnt vmcnt(" #n ")" ::: "memory")

// One k-half (64 k-bytes): 4 B-frags at SEG, then per-m JIT A-read + 4 MFMAs.
#define HALFK(SEG)                                                              \
    {                                                                           \
        i32x4 b0 = *(const i32x4*)(Bb + rbB + 0 * 2048 + (SEG));                \
        i32x4 b1 = *(const i32x4*)(Bb + rbB + 1 * 2048 + (SEG));                \
        i32x4 b2 = *(const i32x4*)(Bb + rbB + 2 * 2048 + (SEG));                \
        i32x4 b3 = *(const i32x4*)(Bb + rbB + 3 * 2048 + (SEG));                \
        _Pragma("unroll")                                                       \
        for (int m = 0; m < 4; ++m) {                                           \
            i32x4 a = *(const i32x4*)(Ab + rbA + m * 2048 + (SEG));             \
            __builtin_amdgcn_s_setprio(1);                                      \
            acc[m][0] = __builtin_amdgcn_mfma_i32_16x16x64_i8(a, b0, acc[m][0], 0, 0, 0); \
            acc[m][1] = __builtin_amdgcn_mfma_i32_16x16x64_i8(a, b1, acc[m][1], 0, 0, 0); \
            acc[m][2] = __builtin_amdgcn_mfma_i32_16x16x64_i8(a, b2, acc[m][2], 0, 0, 0); \
            acc[m][3] = __builtin_amdgcn_mfma_i32_16x16x64_i8(a, b3, acc[m][3], 0, 0, 0); \
            __builtin_amdgcn_s_setprio(0);                                      \
        }                                                                       \
    }

__global__ __launch_bounds__(1024) void gemm_kernel(const signed char* __restrict__ n1,
                                                    const signed char* __restrict__ n2,
                                                    const float* __restrict__ inva,
                                                    const float* __restrict__ invb,
                                                    float* __restrict__ partial) {
    extern __shared__ char smem[];
    int t = threadIdx.x;
    int l = t & 63;
    int w = t >> 6;    // 0..15
    int wr = w >> 2;   // 0..3 -> A 64-row band
    int wc = w & 3;    // 0..3 -> B 64-col band

    // XCD-aware + L2 supertile mapping (1024 blocks, bijective)
    int bid = blockIdx.x;
    int xcd = bid & 7, idx = bid >> 3;
    int br = xcd * 4 + (idx & 3);
    int bc = (idx >> 4) * 4 + ((idx >> 2) & 3);
    int rowbase = br * BM, colbase = bc * BN;

    // staging: thread t covers LDS row sr = t>>3 (+128j), granule t&7;
    // inverse-swizzled global 16B-granule = (t&7) ^ (sr&7)
    int sr = t >> 3;
    int gcol0 = ((t & 7) ^ (sr & 7)) * 16;
    const signed char* Ag = n1 + (size_t)(rowbase + sr) * DIM + gcol0;
    const signed char* Bg = n2 + (size_t)(colbase + sr) * DIM + gcol0;

    i32x4 acc[4][4] = {};   // 64 regs (AGPR)

    // read side: frag row r = l&15 (bands multiples of 64 -> r&7 = l&7),
    // true granule = (l>>4) + 4*ks, slot = granule ^ (l&7)
    int seg0 = (((l >> 4) + 0) ^ (l & 7)) * 16;
    int seg1 = (((l >> 4) + 4) ^ (l & 7)) * 16;
    int rbA = (wr * 64 + (l & 15)) * 128;
    int rbB = (wc * 64 + (l & 15)) * 128;

    // prologue: stage K-tile 0 into parity 0
    stG(Ag, smem, t, 0);         stG(Ag, smem, t, 1);
    stG(Bg, smem + 65536, t, 0); stG(Bg, smem + 65536, t, 1);
    VMW(0); BAR();

    #pragma unroll
    for (int kt = 0; kt < KTILES - 1; ++kt) {
        int db = kt & 1;
        const char* Ab = smem + db * 32768;
        const char* Bb = smem + 65536 + db * 32768;
        char* AnW = smem + (db ^ 1) * 32768;
        char* BnW = smem + 65536 + (db ^ 1) * 32768;
        const signed char* Agn = Ag + (kt + 1) * BKB;
        const signed char* Bgn = Bg + (kt + 1) * BKB;

        // stage next tile, then compute both k-halves (split-ks: B regs reused)
        stG(Agn, AnW, t, 0); stG(Agn, AnW, t, 1);
        stG(Bgn, BnW, t, 0); stG(Bgn, BnW, t, 1);
        HALFK(seg0);
        HALFK(seg1);
        VMW(0); BAR();
    }
    {   // peeled last tile (kt = 5, parity 1): no staging
        const char* Ab = smem + 32768;
        const char* Bb = smem + 65536 + 32768;
        HALFK(seg0);
        HALFK(seg1);
    }

    // ---------------- epilogue: cos = acc * inva[row] * invb[col]; t-Student + row sums ----------------
    // C/D map: row = wr*64 + m*16 + (l>>4)*4 + j (A-side), col = wc*64 + n*16 + (l&15)
    float invb_n[4];
    #pragma unroll
    for (int n = 0; n < 4; ++n)
        invb_n[n] = invb[colbase + wc * 64 + n * 16 + (l & 15)];

    float* red = (float*)smem;  // 256 rows x 4 wc
    __syncthreads();
    #pragma unroll
    for (int m = 0; m < 4; ++m) {
        f32x4 ia = *(const f32x4*)(inva + rowbase + wr * 64 + m * 16 + (l >> 4) * 4);
        #pragma unroll
        for (int j = 0; j < 4; ++j) {
            float s = 0.f;
            #pragma unroll
            for (int n = 0; n < 4; ++n) {
                float cos = (float)acc[m][n][j] * ia[j] * invb_n[n];
                s += tstudent(cos);
            }
            s += __shfl_xor(s, 1);
            s += __shfl_xor(s, 2);
            s += __shfl_xor(s, 4);
            s += __shfl_xor(s, 8);
            if ((l & 15) == 0) {
                int row = wr * 64 + m * 16 + (l >> 4) * 4 + j;
                red[row * 4 + wc] = s;
            }
        }
    }
    __syncthreads();
    if (t < BM) {
        partial[(size_t)bc * N_ROWS + rowbase + t] = red[t * 4 + 0] + red[t * 4 + 1] + red[t * 4 + 2] + red[t * 4 + 3];
    }
}

// ---------------- kernel 3: per-row denom + ratio, per-block sums ----------------
__global__ __launch_bounds__(256) void reduce_kernel(const float* __restrict__ partial,
                                                     const float* __restrict__ num,
                                                     float* __restrict__ blocksum) {
    int row = blockIdx.x * 256 + threadIdx.x;
    float d = 0.f;
    #pragma unroll 8
    for (int ct = 0; ct < NT2; ++ct) d += partial[(size_t)ct * N_ROWS + row];
    float s = num[row] / d;
    for (int off = 32; off; off >>= 1) s += __shfl_down(s, off);
    __shared__ float wsum[4];
    if ((threadIdx.x & 63) == 0) wsum[threadIdx.x >> 6] = s;
    __syncthreads();
    if (threadIdx.x == 0) blocksum[blockIdx.x] = wsum[0] + wsum[1] + wsum[2] + wsum[3];
}

// ---------------- kernel 4: final scalar ----------------
__global__ __launch_bounds__(64) void final_kernel(const float* __restrict__ blocksum,
                                                   float* __restrict__ out) {
    int l = threadIdx.x;
    float s = (l < 32) ? blocksum[l] : 0.f;
    for (int off = 32; off; off >>= 1) s += __shfl_down(s, off);
    if (l == 0) out[0] = -(s / (float)N_ROWS);
}

extern "C" void kernel_launch(void* const* d_in, const int* in_sizes, int n_in,
                              void* d_out, int out_size, void* d_ws, size_t ws_size,
                              hipStream_t stream) {
    const float* z1 = (const float*)d_in[0];
    const float* z2 = (const float*)d_in[1];
    char* ws = (char*)d_ws;
    const size_t n_bytes = (size_t)N_ROWS * DIM;   // 6,291,456 (int8)
    signed char* n1 = (signed char*)ws;
    signed char* n2 = (signed char*)(ws + n_bytes);
    size_t base2 = 2 * n_bytes;
    float* num      = (float*)(ws + base2);                    // 32 KB
    float* inva     = (float*)(ws + base2 + 32768);            // 32 KB
    float* invb     = (float*)(ws + base2 + 65536);            // 32 KB
    float* partial  = (float*)(ws + base2 + 98304);            // 1 MB used
    float* blocksum = (float*)(ws + base2 + 98304 + 2097152);  // 128 B

    hipFuncSetAttribute((const void*)gemm_kernel,
                        hipFuncAttributeMaxDynamicSharedMemorySize, LDS_BYTES);

    norm_kernel<<<N_ROWS, 256, 0, stream>>>(z1, z2, n1, n2, num, inva, invb);
    gemm_kernel<<<NT2 * NT2, 1024, LDS_BYTES, stream>>>(n1, n2, inva, invb, partial);
    reduce_kernel<<<N_ROWS / 256, 256, 0, stream>>>(partial, num, blocksum);
    final_kernel<<<1, 64, 0, stream>>>(blocksum, (float*)d_out);
}